// Round 3
// baseline (535.335 us; speedup 1.0000x reference)
//
#include <hip/hip_runtime.h>
#include <math.h>

namespace {

constexpr int NUM_ENVS = 16384;
constexpr int OUT_DIM = 512;
constexpr int FLAT = 1024;

typedef float floatx4 __attribute__((ext_vector_type(4)));
typedef short shortx8 __attribute__((ext_vector_type(8)));

__device__ __forceinline__ float fast_sigmoid(float v) {
    const float e = __builtin_amdgcn_exp2f(-v * 1.44269504088896340736f);
    return __builtin_amdgcn_rcpf(1.0f + e);
}
__device__ __forceinline__ float fast_tanh(float v) {
    const float e = __builtin_amdgcn_exp2f(v * 2.88539008177792681472f);
    return 1.0f - 2.0f * __builtin_amdgcn_rcpf(1.0f + e);
}
__device__ __forceinline__ unsigned short f2bf(float f) {
    unsigned int u = __float_as_uint(f);
    u = (u + 0x7FFFu + ((u >> 16) & 1u)) >> 16;  // RNE
    return (unsigned short)u;
}
__device__ __forceinline__ shortx8 pack8(const float4& f0, const float4& f1) {
    shortx8 o;
    o[0] = (short)f2bf(f0.x); o[1] = (short)f2bf(f0.y);
    o[2] = (short)f2bf(f0.z); o[3] = (short)f2bf(f0.w);
    o[4] = (short)f2bf(f1.x); o[5] = (short)f2bf(f1.y);
    o[6] = (short)f2bf(f1.z); o[7] = (short)f2bf(f1.w);
    return o;
}

// ws float offsets
constexpr int WS_FLAG = 0;
constexpr int WS_WGF  = 64;                  // 16 slots *64*8 = 8192 bf16 = 4096 f
constexpr int WS_WCF  = WS_WGF + 4096;       // 48 slots = 24576 bf16 = 12288 f
constexpr int WS_WLB  = WS_WCF + 12288;      // 524288 bf16 = 262144 f
constexpr int WS_GB   = WS_WLB + 262144;     // gcn -> hb (in-place): [262144][64] bf16

// prep: block 0 = edge dtype detect; rest pack MFMA B-fragments (bf16,
// per-lane order so kernels load frags with one coalesced 16B read).
__global__ void prep_kernel(const int* __restrict__ edges_i32,
                            const float* __restrict__ Wg,
                            const float* __restrict__ Wih,
                            const float* __restrict__ Whh,
                            const float* __restrict__ Wlin,
                            float* __restrict__ ws) {
    if (blockIdx.x == 0) {
        __shared__ int any_nonzero;
        if (threadIdx.x == 0) any_nonzero = 0;
        __syncthreads();
        if (threadIdx.x < 128 && edges_i32[2 * threadIdx.x + 1] != 0)
            atomicOr(&any_nonzero, 1);
        __syncthreads();
        if (threadIdx.x == 0) ((int*)ws)[WS_FLAG] = (any_nonzero == 0) ? 1 : 0;
        return;
    }
    const int t = ((int)blockIdx.x - 1) * 256 + (int)threadIdx.x;
    if (t < 8192) {
        // WgF: slot = nt*4+ks; B[n][k], n = Wg col, k = Wg row
        const int jj = t & 7, lane = (t >> 3) & 63, slot = t >> 9;
        const int nt = slot >> 2, ks = slot & 3;
        const int n = nt * 16 + (lane & 15);
        const int k = ks * 32 + ((lane >> 4) & 3) * 8 + jj;
        ((unsigned short*)(ws + WS_WGF))[t] = f2bf(Wg[k * 64 + n]);
    } else if (t < 32768) {
        const int u = t - 8192;
        const int jj = u & 7, lane = (u >> 3) & 63, slot = u >> 9; // 0..47
        const int q8 = ((lane >> 4) & 3) * 8 + jj;
        float val;
        if (slot < 16) {           // r gate, K=128 combined [Wih_r | Whh_r]
            const int nt = slot >> 2, ks = slot & 3;
            const int n = nt * 16 + (lane & 15);
            const int k = ks * 32 + q8;
            val = (k < 64) ? Wih[n * 64 + k] : Whh[n * 64 + (k - 64)];
        } else if (slot < 32) {    // z gate, K=128 combined
            const int s = slot - 16, nt = s >> 2, ks = s & 3;
            const int n = 64 + nt * 16 + (lane & 15);
            const int k = ks * 32 + q8;
            val = (k < 64) ? Wih[n * 64 + k] : Whh[n * 64 + (k - 64)];
        } else if (slot < 40) {    // nx: Wih_n, K=64
            const int s = slot - 32, nt = s >> 1, ks = s & 1;
            const int n = 128 + nt * 16 + (lane & 15);
            val = Wih[n * 64 + ks * 32 + q8];
        } else {                   // nh: Whh_n, K=64
            const int s = slot - 40, nt = s >> 1, ks = s & 1;
            const int n = 128 + nt * 16 + (lane & 15);
            val = Whh[n * 64 + ks * 32 + q8];
        }
        ((unsigned short*)(ws + WS_WCF))[u] = f2bf(val);
    } else if (t < 32768 + 524288) {
        const int u = t - 32768;
        ((unsigned short*)(ws + WS_WLB))[u] = f2bf(Wlin[u]);
    }
}

// K1: one env per 64-thread (single-wave) workgroup. All __syncthreads are
// single-wave fences (no cross-wave coupling); 5.6 KB LDS -> ~16 blocks/CU.
// xw = bf16(x)@Wg via MFMA (A-frags direct global->reg), adj[16x16]@xw
// scalar agg, writes gcn bf16 [262144][64].
__global__ __launch_bounds__(64, 4) void gcn_env_kernel(
    const float* __restrict__ x,
    const void*  __restrict__ edges,
    const unsigned short* __restrict__ WgF,
    const float* __restrict__ bg,
    unsigned short* __restrict__ gcn,
    const int* __restrict__ flag64)
{
    const int env = blockIdx.x;
    const int lane = threadIdx.x;

    __shared__ float xw_s[16 * 68];     // 4352 B
    __shared__ float adj_s[16][17];     // 1088 B
    __shared__ int   deg_s[16];
    __shared__ float dinv_s[16];
    __shared__ float invdeg_s[16];

    const int ar = lane & 15;
    const int aq = lane >> 4;

    // x A-fragments: direct global -> regs
    float4 xf[4][2];
    #pragma unroll
    for (int ks = 0; ks < 4; ++ks) {
        const float4* p = (const float4*)(x + ((size_t)env * 16 + ar) * 128 + ks * 32 + aq * 8);
        xf[ks][0] = p[0];
        xf[ks][1] = p[1];
    }

    // edges -> regs (2 per lane)
    const bool is64 = (*flag64 != 0);
    int rv[2], cv[2];
    const size_t ebase = (size_t)env * 256;
    #pragma unroll
    for (int t = 0; t < 2; ++t) {
        const int idx = lane + 64 * t;
        if (is64) {
            rv[t] = (int)((const long long*)edges)[ebase + idx];
            cv[t] = (int)((const long long*)edges)[ebase + 128 + idx];
        } else {
            rv[t] = ((const int*)edges)[ebase + idx];
            cv[t] = ((const int*)edges)[ebase + 128 + idx];
        }
    }

    // zero deg + adj
    if (lane < 16) deg_s[lane] = 0;
    {
        float* ap = &adj_s[0][0];
        #pragma unroll
        for (int i = 0; i < 5; ++i) {
            const int j = lane + 64 * i;
            if (j < 272) ap[j] = 0.0f;
        }
    }
    __syncthreads();

    // degree atomics (latency overlaps MFMA below)
    #pragma unroll
    for (int t = 0; t < 2; ++t) atomicAdd(&deg_s[cv[t]], 1);

    // xw MFMA
    shortx8 afr[4];
    #pragma unroll
    for (int ks = 0; ks < 4; ++ks) afr[ks] = pack8(xf[ks][0], xf[ks][1]);
    floatx4 acc[4];
    #pragma unroll
    for (int nt = 0; nt < 4; ++nt) acc[nt] = (floatx4)(0.0f);
    #pragma unroll
    for (int nt = 0; nt < 4; ++nt) {
        #pragma unroll
        for (int ks = 0; ks < 4; ++ks) {
            const shortx8 bfr = *(const shortx8*)&WgF[((nt * 4 + ks) * 64 + lane) * 8];
            acc[nt] = __builtin_amdgcn_mfma_f32_16x16x32_bf16(afr[ks], bfr, acc[nt], 0, 0, 0);
        }
    }
    __syncthreads();  // deg atomics complete

    if (lane < 16) {
        const float d = 1.0f + (float)deg_s[lane];
        dinv_s[lane] = rsqrtf(d);
        invdeg_s[lane] = 1.0f / d;
    }
    // store xw (rows aq*4+i, col nt*16+ar)
    #pragma unroll
    for (int nt = 0; nt < 4; ++nt)
        #pragma unroll
        for (int i = 0; i < 4; ++i)
            xw_s[(aq * 4 + i) * 68 + nt * 16 + ar] = acc[nt][i];
    __syncthreads();  // dinv + xw visible

    // adjacency accumulate
    #pragma unroll
    for (int t = 0; t < 2; ++t)
        atomicAdd(&adj_s[cv[t]][rv[t]], dinv_s[rv[t]] * dinv_s[cv[t]]);
    if (lane < 16)
        atomicAdd(&adj_s[lane][lane], invdeg_s[lane]);
    __syncthreads();

    // agg = adj @ xw, + bg, write bf16 to global
    {
        const int cl = lane >> 2, q = lane & 3;
        float accs[16];
        #pragma unroll
        for (int m = 0; m < 16; ++m) accs[m] = 0.0f;
        for (int r16 = 0; r16 < 16; ++r16) {
            const float a = adj_s[cl][r16];
            const float4* xr = (const float4*)&xw_s[r16 * 68 + q * 16];
            #pragma unroll
            for (int jq = 0; jq < 4; ++jq) {
                const float4 v = xr[jq];
                accs[4 * jq + 0] += a * v.x;
                accs[4 * jq + 1] += a * v.y;
                accs[4 * jq + 2] += a * v.z;
                accs[4 * jq + 3] += a * v.w;
            }
        }
        unsigned short* dst = gcn + ((size_t)env * 16 + cl) * 64 + q * 16;
        shortx8 o0, o1;
        #pragma unroll
        for (int m = 0; m < 8; ++m) o0[m] = (short)f2bf(accs[m] + bg[q * 16 + m]);
        #pragma unroll
        for (int m = 0; m < 8; ++m) o1[m] = (short)f2bf(accs[8 + m] + bg[q * 16 + 8 + m]);
        *(shortx8*)dst = o0;
        *(shortx8*)(dst + 8) = o1;
    }
}

// K2: flat gates GEMM + fused GRU epilogue over all 262144 node rows.
// W staged ONCE into 48 KB LDS per block, amortized over 256 rows
// (4 waves x 4 tiles of 16). A-frags direct global->reg: gcn bf16 (ks 0-1)
// + packed h_prev (ks 2-3). One barrier total. hb overwrites gcn in place
// (read-before-write per tile via load->MFMA->store dependency; rows are
// tile-exclusive). [262144][64] row-major == [16384][1024] flat, so the
// logits kernel consumes it unchanged.
__global__ __launch_bounds__(256, 3) void gru_gemm_kernel(
    unsigned short* __restrict__ gb,         // in: gcn; out: hb (in-place)
    const float* __restrict__ h_prev,
    const unsigned short* __restrict__ WcF,
    const float* __restrict__ bih,
    const float* __restrict__ bhh,
    float* __restrict__ next_h)
{
    const int tid = threadIdx.x;
    const int lane = tid & 63;
    const int w = tid >> 6;

    __shared__ unsigned short W_s[48 * 64 * 8];   // 49152 B

    // stage W fragments (coalesced, 12 x uint4 per thread)
    {
        const uint4* src = (const uint4*)WcF;
        uint4* dst = (uint4*)W_s;
        #pragma unroll
        for (int jq = 0; jq < 12; ++jq) dst[tid + 256 * jq] = src[tid + 256 * jq];
    }

    // hoist biases (depend only on lane)
    const int cl2 = lane & 15;
    const int rq = lane >> 4;
    float brv[4], bzv[4], bnxv[4], bnhv[4];
    #pragma unroll
    for (int tp = 0; tp < 4; ++tp) {
        const int f = tp * 16 + cl2;
        brv[tp] = bih[f] + bhh[f];
        bzv[tp] = bih[64 + f] + bhh[64 + f];
        bnxv[tp] = bih[128 + f];
        bnhv[tp] = bhh[128 + f];
    }
    __syncthreads();  // W_s ready; no further barriers

    const int rl = lane & 15;
    const int aq = rq;

    #pragma unroll 1
    for (int t = 0; t < 4; ++t) {
        const size_t base = (size_t)blockIdx.x * 256 + (size_t)w * 64 + t * 16;

        // A-fragments: gcn bf16 (cols 0-63) + packed h (cols 64-127)
        shortx8 afr[4];
        const unsigned short* gp = gb + (base + rl) * 64;
        afr[0] = *(const shortx8*)(gp + aq * 8);
        afr[1] = *(const shortx8*)(gp + 32 + aq * 8);
        const float* hp4 = h_prev + (base + rl) * 64;
        {
            const float4* pa = (const float4*)(hp4 + aq * 8);
            afr[2] = pack8(pa[0], pa[1]);
            const float4* pb = (const float4*)(hp4 + 32 + aq * 8);
            afr[3] = pack8(pb[0], pb[1]);
        }

        floatx4 aR[4], aZ[4], aNX[4], aNH[4];
        #pragma unroll
        for (int nt = 0; nt < 4; ++nt) {
            aR[nt] = (floatx4)(0.0f); aZ[nt] = (floatx4)(0.0f);
            aNX[nt] = (floatx4)(0.0f); aNH[nt] = (floatx4)(0.0f);
        }
        #pragma unroll
        for (int nt = 0; nt < 4; ++nt) {
            #pragma unroll
            for (int ks = 0; ks < 4; ++ks) {
                const shortx8 bfr = *(const shortx8*)&W_s[((nt * 4 + ks) * 64 + lane) * 8];
                aR[nt] = __builtin_amdgcn_mfma_f32_16x16x32_bf16(afr[ks], bfr, aR[nt], 0, 0, 0);
            }
            #pragma unroll
            for (int ks = 0; ks < 4; ++ks) {
                const shortx8 bfr = *(const shortx8*)&W_s[((16 + nt * 4 + ks) * 64 + lane) * 8];
                aZ[nt] = __builtin_amdgcn_mfma_f32_16x16x32_bf16(afr[ks], bfr, aZ[nt], 0, 0, 0);
            }
            #pragma unroll
            for (int ks = 0; ks < 2; ++ks) {
                const shortx8 bfr = *(const shortx8*)&W_s[((32 + nt * 2 + ks) * 64 + lane) * 8];
                aNX[nt] = __builtin_amdgcn_mfma_f32_16x16x32_bf16(afr[ks], bfr, aNX[nt], 0, 0, 0);
            }
            #pragma unroll
            for (int ks = 0; ks < 2; ++ks) {
                const shortx8 bfr = *(const shortx8*)&W_s[((40 + nt * 2 + ks) * 64 + lane) * 8];
                aNH[nt] = __builtin_amdgcn_mfma_f32_16x16x32_bf16(afr[ks + 2], bfr, aNH[nt], 0, 0, 0);
            }
        }

        // GRU epilogue (in-lane; f32 h_prev re-read hits L1 lines already
        // fetched by the h frag loads)
        #pragma unroll
        for (int tp = 0; tp < 4; ++tp) {
            const int f = tp * 16 + cl2;
            #pragma unroll
            for (int i = 0; i < 4; ++i) {
                const size_t row = base + rq * 4 + i;
                const float hp = h_prev[row * 64 + f];
                const float r = fast_sigmoid(aR[tp][i] + brv[tp]);
                const float z = fast_sigmoid(aZ[tp][i] + bzv[tp]);
                const float n = fast_tanh(aNX[tp][i] + bnxv[tp] + r * (aNH[tp][i] + bnhv[tp]));
                const float hv = (1.0f - z) * n + z * hp;
                next_h[row * 64 + f] = hv;
                gb[row * 64 + f] = f2bf(hv);
            }
        }
    }
}

// K_D: logits = hb[16384,1024] @ Wlb[512,1024]^T + b_lin (unchanged)
__global__ __launch_bounds__(256, 4) void logits_mfma_kernel(
    const unsigned short* __restrict__ A,
    const unsigned short* __restrict__ B,
    const float* __restrict__ bias,
    float* __restrict__ C)
{
    __shared__ __align__(16) unsigned short As[128 * 64];
    __shared__ __align__(16) unsigned short Bs[128 * 64];

    const int tid = threadIdx.x;
    const int lane = tid & 63;
    const int wave = tid >> 6;
    const int wr = wave >> 1;
    const int wc = wave & 1;
    const int m0 = blockIdx.y * 128;
    const int n0 = blockIdx.x * 128;
    const int lr = tid >> 3;
    const int lk = tid & 7;

    floatx4 acc[4][4];
    #pragma unroll
    for (int i = 0; i < 4; ++i)
        #pragma unroll
        for (int jn = 0; jn < 4; ++jn)
            acc[i][jn] = (floatx4)(0.0f);

    for (int kt = 0; kt < 16; ++kt) {
        const int k0 = kt * 64;
        __syncthreads();
        #pragma unroll
        for (int i = 0; i < 4; ++i) {
            const int r = lr + 32 * i;
            const uint4 va = *(const uint4*)&A[(size_t)(m0 + r) * FLAT + k0 + lk * 8];
            *(uint4*)&As[r * 64 + ((lk ^ (r & 7)) * 8)] = va;
            const uint4 vb = *(const uint4*)&B[(size_t)(n0 + r) * FLAT + k0 + lk * 8];
            *(uint4*)&Bs[r * 64 + ((lk ^ (r & 7)) * 8)] = vb;
        }
        __syncthreads();
        #pragma unroll
        for (int s = 0; s < 2; ++s) {
            const int kg = s * 4 + (lane >> 4);
            const int sw = (kg ^ (lane & 7)) * 8;
            shortx8 af[4], bf[4];
            #pragma unroll
            for (int t = 0; t < 4; ++t) {
                af[t] = *(const shortx8*)&As[(wr * 64 + t * 16 + (lane & 15)) * 64 + sw];
                bf[t] = *(const shortx8*)&Bs[(wc * 64 + t * 16 + (lane & 15)) * 64 + sw];
            }
            #pragma unroll
            for (int mt = 0; mt < 4; ++mt)
                #pragma unroll
                for (int nt = 0; nt < 4; ++nt)
                    acc[mt][nt] = __builtin_amdgcn_mfma_f32_16x16x32_bf16(
                        af[mt], bf[nt], acc[mt][nt], 0, 0, 0);
        }
    }

    const int col_l = lane & 15;
    const int rg = lane >> 4;
    #pragma unroll
    for (int nt = 0; nt < 4; ++nt) {
        const int col = n0 + wc * 64 + nt * 16 + col_l;
        const float bv = bias[col];
        #pragma unroll
        for (int mt = 0; mt < 4; ++mt) {
            const int row = m0 + wr * 64 + mt * 16 + rg * 4;
            #pragma unroll
            for (int i = 0; i < 4; ++i) {
                C[(size_t)(row + i) * OUT_DIM + col] = acc[mt][nt][i] + bv;
            }
        }
    }
}

} // namespace

extern "C" void kernel_launch(void* const* d_in, const int* in_sizes, int n_in,
                              void* d_out, int out_size, void* d_ws, size_t ws_size,
                              hipStream_t stream) {
    const float* x    = (const float*)d_in[0];
    const void*  ei   = d_in[1];
    const float* h0   = (const float*)d_in[2];
    const float* Wg   = (const float*)d_in[3];
    const float* bg   = (const float*)d_in[4];
    const float* Wih  = (const float*)d_in[5];
    const float* Whh  = (const float*)d_in[6];
    const float* bih  = (const float*)d_in[7];
    const float* bhh  = (const float*)d_in[8];
    const float* Wlin = (const float*)d_in[9];
    const float* blin = (const float*)d_in[10];

    float* out = (float*)d_out;
    float* logits = out;                               // [16384, 512]
    float* next_h = out + (size_t)NUM_ENVS * OUT_DIM;  // [16384, 16, 64]

    float* wsf = (float*)d_ws;
    int* flag = (int*)(wsf + WS_FLAG);
    unsigned short* WgF = (unsigned short*)(wsf + WS_WGF);
    unsigned short* WcF = (unsigned short*)(wsf + WS_WCF);
    unsigned short* Wlb = (unsigned short*)(wsf + WS_WLB);
    unsigned short* gb  = (unsigned short*)(wsf + WS_GB);  // gcn -> hb in place

    prep_kernel<<<2177, 256, 0, stream>>>((const int*)ei, Wg, Wih, Whh, Wlin, wsf);
    gcn_env_kernel<<<NUM_ENVS, 64, 0, stream>>>(x, ei, WgF, bg, gb, flag);
    gru_gemm_kernel<<<1024, 256, 0, stream>>>(gb, h0, WcF, bih, bhh, next_h);
    dim3 g2(OUT_DIM / 128, NUM_ENVS / 128);
    logits_mfma_kernel<<<g2, 256, 0, stream>>>(gb, Wlb, blin, logits);
}

// Round 4
// 388.232 us; speedup vs baseline: 1.3789x; 1.3789x over previous
//
#include <hip/hip_runtime.h>
#include <math.h>

namespace {

constexpr int NUM_ENVS = 16384;
constexpr int OUT_DIM = 512;
constexpr int FLAT = 1024;

typedef float floatx4 __attribute__((ext_vector_type(4)));
typedef short shortx8 __attribute__((ext_vector_type(8)));

__device__ __forceinline__ float fast_sigmoid(float v) {
    const float e = __builtin_amdgcn_exp2f(-v * 1.44269504088896340736f);
    return __builtin_amdgcn_rcpf(1.0f + e);
}
__device__ __forceinline__ float fast_tanh(float v) {
    const float e = __builtin_amdgcn_exp2f(v * 2.88539008177792681472f);
    return 1.0f - 2.0f * __builtin_amdgcn_rcpf(1.0f + e);
}
__device__ __forceinline__ unsigned short f2bf(float f) {
    unsigned int u = __float_as_uint(f);
    u = (u + 0x7FFFu + ((u >> 16) & 1u)) >> 16;  // RNE
    return (unsigned short)u;
}
__device__ __forceinline__ shortx8 pack8(const float4& f0, const float4& f1) {
    shortx8 o;
    o[0] = (short)f2bf(f0.x); o[1] = (short)f2bf(f0.y);
    o[2] = (short)f2bf(f0.z); o[3] = (short)f2bf(f0.w);
    o[4] = (short)f2bf(f1.x); o[5] = (short)f2bf(f1.y);
    o[6] = (short)f2bf(f1.z); o[7] = (short)f2bf(f1.w);
    return o;
}

// ws float offsets
constexpr int WS_FLAG = 0;
constexpr int WS_WGF  = 64;                  // 16 slots *64*8 = 8192 bf16 = 4096 f
constexpr int WS_WCF  = WS_WGF + 4096;       // 48 slots = 24576 bf16 = 12288 f
constexpr int WS_WLB  = WS_WCF + 12288;      // 524288 bf16 = 262144 f
constexpr int WS_GB   = WS_WLB + 262144;     // hb: [262144][64] bf16

// prep: block 0 = edge dtype detect; rest pack MFMA B-fragments (bf16,
// per-lane order so kernels load frags with one coalesced 16B read).
__global__ void prep_kernel(const int* __restrict__ edges_i32,
                            const float* __restrict__ Wg,
                            const float* __restrict__ Wih,
                            const float* __restrict__ Whh,
                            const float* __restrict__ Wlin,
                            float* __restrict__ ws) {
    if (blockIdx.x == 0) {
        __shared__ int any_nonzero;
        if (threadIdx.x == 0) any_nonzero = 0;
        __syncthreads();
        if (threadIdx.x < 128 && edges_i32[2 * threadIdx.x + 1] != 0)
            atomicOr(&any_nonzero, 1);
        __syncthreads();
        if (threadIdx.x == 0) ((int*)ws)[WS_FLAG] = (any_nonzero == 0) ? 1 : 0;
        return;
    }
    const int t = ((int)blockIdx.x - 1) * 256 + (int)threadIdx.x;
    if (t < 8192) {
        // WgF: slot = nt*4+ks; B[n][k], n = Wg col, k = Wg row
        const int jj = t & 7, lane = (t >> 3) & 63, slot = t >> 9;
        const int nt = slot >> 2, ks = slot & 3;
        const int n = nt * 16 + (lane & 15);
        const int k = ks * 32 + ((lane >> 4) & 3) * 8 + jj;
        ((unsigned short*)(ws + WS_WGF))[t] = f2bf(Wg[k * 64 + n]);
    } else if (t < 32768) {
        const int u = t - 8192;
        const int jj = u & 7, lane = (u >> 3) & 63, slot = u >> 9; // 0..47
        const int q8 = ((lane >> 4) & 3) * 8 + jj;
        float val;
        if (slot < 16) {           // r gate, K=128 combined [Wih_r | Whh_r]
            const int nt = slot >> 2, ks = slot & 3;
            const int n = nt * 16 + (lane & 15);
            const int k = ks * 32 + q8;
            val = (k < 64) ? Wih[n * 64 + k] : Whh[n * 64 + (k - 64)];
        } else if (slot < 32) {    // z gate, K=128 combined
            const int s = slot - 16, nt = s >> 2, ks = s & 3;
            const int n = 64 + nt * 16 + (lane & 15);
            const int k = ks * 32 + q8;
            val = (k < 64) ? Wih[n * 64 + k] : Whh[n * 64 + (k - 64)];
        } else if (slot < 40) {    // nx: Wih_n, K=64
            const int s = slot - 32, nt = s >> 1, ks = s & 1;
            const int n = 128 + nt * 16 + (lane & 15);
            val = Wih[n * 64 + ks * 32 + q8];
        } else {                   // nh: Whh_n, K=64
            const int s = slot - 40, nt = s >> 1, ks = s & 1;
            const int n = 128 + nt * 16 + (lane & 15);
            val = Whh[n * 64 + ks * 32 + q8];
        }
        ((unsigned short*)(ws + WS_WCF))[u] = f2bf(val);
    } else if (t < 32768 + 524288) {
        const int u = t - 32768;
        ((unsigned short*)(ws + WS_WLB))[u] = f2bf(Wlin[u]);
    }
}

// Fused GCN+GRU: 4 envs (64 node rows) per block.
// v2: h_prev NOT staged in LDS (fragments load global->reg at kernel start,
// packed to bf16; epilogue re-reads f32 h from L1/L2). A_s holds only the
// gcn half -> LDS ~34 KB -> 4 blocks/CU.
__global__ __launch_bounds__(256, 4) void fused_gcn_gru_kernel(
    const float* __restrict__ x,
    const void*  __restrict__ edges,
    const unsigned short* __restrict__ WgF,
    const float* __restrict__ bg,
    const float* __restrict__ h_prev,
    const unsigned short* __restrict__ WcF,
    const float* __restrict__ bih,
    const float* __restrict__ bhh,
    float* __restrict__ next_h,
    unsigned short* __restrict__ hb,
    const int* __restrict__ flag64)
{
    const int b = blockIdx.x;
    const int tid = threadIdx.x;
    const int lane = tid & 63;
    const int w = tid >> 6;

    __shared__ float xw_s[64 * 68];               // 17408 B
    __shared__ unsigned short A_s[64 * 72];       // 9216 B (gcn only)
    __shared__ int rc_s[512];                     // 2048 B
    __shared__ float adj_s[4][16][17];            // 4352 B
    __shared__ int deg_s[4][16];
    __shared__ float dinv_s[4][16];
    __shared__ float invdeg_s[4][16];
    // total ~34 KB -> 4 blocks/CU

    const int ar = w * 16 + (lane & 15);          // this lane's A-row
    const int aq = (lane >> 4) & 3;

    // early loads: x A-fragments (direct global -> regs)
    float4 xf[4][2];
    #pragma unroll
    for (int ks = 0; ks < 4; ++ks) {
        const float4* p = (const float4*)(x + ((size_t)b * 64 + ar) * 128 + ks * 32 + aq * 8);
        xf[ks][0] = p[0];
        xf[ks][1] = p[1];
    }
    // early loads: h fragments (global -> regs, packed bf16 immediately).
    // HBM latency overlaps the entire GCN phase.
    shortx8 hfr2, hfr3;
    {
        const float* hp4 = h_prev + ((size_t)b * 64 + ar) * 64;
        const float4* pa = (const float4*)(hp4 + aq * 8);
        hfr2 = pack8(pa[0], pa[1]);
        const float4* pb = (const float4*)(hp4 + 32 + aq * 8);
        hfr3 = pack8(pb[0], pb[1]);
    }

    // zero adj/deg
    {
        float* ap = &adj_s[0][0][0];
        for (int i = tid; i < 4 * 16 * 17; i += 256) ap[i] = 0.0f;
        if (tid < 64) deg_s[tid >> 4][tid & 15] = 0;
    }
    // stage edges (4 envs x 128), packed
    const bool is64 = (*flag64 != 0);
    #pragma unroll
    for (int t = 0; t < 2; ++t) {
        const int e = tid + 256 * t;
        const int el = e >> 7, idx = e & 127;
        const size_t base = ((size_t)b * 4 + el) * 256;
        int rv, cv;
        if (is64) {
            rv = (int)((const long long*)edges)[base + idx];
            cv = (int)((const long long*)edges)[base + 128 + idx];
        } else {
            rv = ((const int*)edges)[base + idx];
            cv = ((const int*)edges)[base + 128 + idx];
        }
        rc_s[e] = rv | (cv << 8);
    }
    __syncthreads();

    // degree atomics (overlap with MFMA below)
    #pragma unroll
    for (int t = 0; t < 2; ++t) {
        const int e = tid + 256 * t;
        atomicAdd(&deg_s[e >> 7][(rc_s[e] >> 8) & 15], 1);
    }

    // gcn MFMA: wave w owns rows w*16..w*16+15, all 4 n-tiles.
    shortx8 afr[4];
    #pragma unroll
    for (int ks = 0; ks < 4; ++ks) afr[ks] = pack8(xf[ks][0], xf[ks][1]);
    floatx4 acc[4];
    #pragma unroll
    for (int nt = 0; nt < 4; ++nt) acc[nt] = (floatx4)(0.0f);
    #pragma unroll
    for (int nt = 0; nt < 4; ++nt) {
        #pragma unroll
        for (int ks = 0; ks < 4; ++ks) {
            const shortx8 bfr = *(const shortx8*)&WgF[((nt * 4 + ks) * 64 + lane) * 8];
            acc[nt] = __builtin_amdgcn_mfma_f32_16x16x32_bf16(afr[ks], bfr, acc[nt], 0, 0, 0);
        }
    }
    __syncthreads();  // deg atomics complete

    if (tid < 64) {
        const float d = 1.0f + (float)deg_s[tid >> 4][tid & 15];
        dinv_s[tid >> 4][tid & 15] = rsqrtf(d);
        invdeg_s[tid >> 4][tid & 15] = 1.0f / d;
    }
    // store xw fp32
    #pragma unroll
    for (int nt = 0; nt < 4; ++nt)
        #pragma unroll
        for (int i = 0; i < 4; ++i)
            xw_s[(w * 16 + aq * 4 + i) * 68 + nt * 16 + (lane & 15)] = acc[nt][i];
    __syncthreads();  // dinv + xw ready

    // adjacency accumulate
    #pragma unroll
    for (int t = 0; t < 2; ++t) {
        const int e = tid + 256 * t;
        const int el = e >> 7;
        const int r = rc_s[e] & 15, c = (rc_s[e] >> 8) & 15;
        atomicAdd(&adj_s[el][c][r], dinv_s[el][r] * dinv_s[el][c]);
    }
    if (tid < 64)
        atomicAdd(&adj_s[tid >> 4][tid & 15][tid & 15], invdeg_s[tid >> 4][tid & 15]);
    __syncthreads();

    // agg = adj @ xw, + bg, bf16 -> A_s (gcn half only)
    {
        const int ro = tid >> 2, q = tid & 3;
        const int el = ro >> 4, cl = ro & 15;
        float accs[16];
        #pragma unroll
        for (int m = 0; m < 16; ++m) accs[m] = 0.0f;
        for (int r16 = 0; r16 < 16; ++r16) {
            const float a = adj_s[el][cl][r16];
            const float4* xr = (const float4*)&xw_s[(el * 16 + r16) * 68 + q * 16];
            #pragma unroll
            for (int jq = 0; jq < 4; ++jq) {
                const float4 v = xr[jq];
                accs[4 * jq + 0] += a * v.x;
                accs[4 * jq + 1] += a * v.y;
                accs[4 * jq + 2] += a * v.z;
                accs[4 * jq + 3] += a * v.w;
            }
        }
        unsigned short* dst = &A_s[ro * 72 + q * 16];
        shortx8 o0, o1;
        #pragma unroll
        for (int m = 0; m < 8; ++m) o0[m] = (short)f2bf(accs[m] + bg[q * 16 + m]);
        #pragma unroll
        for (int m = 0; m < 8; ++m) o1[m] = (short)f2bf(accs[8 + m] + bg[q * 16 + 8 + m]);
        *(shortx8*)dst = o0;
        *(shortx8*)(dst + 8) = o1;
    }
    __syncthreads();  // A_s (gcn) complete

    // gates GEMM; A = [gcn (LDS) | h (regs)]; B-frags from global (L2).
    shortx8 gfr[4];
    gfr[0] = *(const shortx8*)&A_s[ar * 72 + aq * 8];
    gfr[1] = *(const shortx8*)&A_s[ar * 72 + 32 + aq * 8];
    gfr[2] = hfr2;
    gfr[3] = hfr3;
    floatx4 aR[4], aZ[4], aNX[4], aNH[4];
    #pragma unroll
    for (int nt = 0; nt < 4; ++nt) {
        aR[nt] = (floatx4)(0.0f); aZ[nt] = (floatx4)(0.0f);
        aNX[nt] = (floatx4)(0.0f); aNH[nt] = (floatx4)(0.0f);
    }
    #pragma unroll
    for (int nt = 0; nt < 4; ++nt) {
        #pragma unroll
        for (int ks = 0; ks < 4; ++ks) {
            const shortx8 bfr = *(const shortx8*)&WcF[((nt * 4 + ks) * 64 + lane) * 8];
            aR[nt] = __builtin_amdgcn_mfma_f32_16x16x32_bf16(gfr[ks], bfr, aR[nt], 0, 0, 0);
        }
        #pragma unroll
        for (int ks = 0; ks < 4; ++ks) {
            const shortx8 bfr = *(const shortx8*)&WcF[((16 + nt * 4 + ks) * 64 + lane) * 8];
            aZ[nt] = __builtin_amdgcn_mfma_f32_16x16x32_bf16(gfr[ks], bfr, aZ[nt], 0, 0, 0);
        }
        #pragma unroll
        for (int ks = 0; ks < 2; ++ks) {
            const shortx8 bfr = *(const shortx8*)&WcF[((32 + nt * 2 + ks) * 64 + lane) * 8];
            aNX[nt] = __builtin_amdgcn_mfma_f32_16x16x32_bf16(gfr[ks], bfr, aNX[nt], 0, 0, 0);
        }
        #pragma unroll
        for (int ks = 0; ks < 2; ++ks) {
            const shortx8 bfr = *(const shortx8*)&WcF[((40 + nt * 2 + ks) * 64 + lane) * 8];
            aNH[nt] = __builtin_amdgcn_mfma_f32_16x16x32_bf16(gfr[ks + 2], bfr, aNH[nt], 0, 0, 0);
        }
    }

    // GRU epilogue (in-lane; fast transcendentals; f32 h re-read hits L1/L2)
    const int cl2 = lane & 15;
    const int rq = (lane >> 4) & 3;
    #pragma unroll
    for (int tp = 0; tp < 4; ++tp) {
        const int f = tp * 16 + cl2;
        const float br = bih[f] + bhh[f];
        const float bz = bih[64 + f] + bhh[64 + f];
        const float bnx = bih[128 + f];
        const float bnh = bhh[128 + f];
        #pragma unroll
        for (int i = 0; i < 4; ++i) {
            const int rl = w * 16 + rq * 4 + i;
            const size_t row = (size_t)b * 64 + rl;
            const float hp = h_prev[row * 64 + f];
            const float r = fast_sigmoid(aR[tp][i] + br);
            const float z = fast_sigmoid(aZ[tp][i] + bz);
            const float n = fast_tanh(aNX[tp][i] + bnx + r * (aNH[tp][i] + bnh));
            const float hv = (1.0f - z) * n + z * hp;
            next_h[row * 64 + f] = hv;
            hb[row * 64 + f] = f2bf(hv);
        }
    }
}

// K_D: logits = hb[16384,1024] @ Wlb[512,1024]^T + b_lin.
// v2: double-buffered LDS + reg-staged prefetch (T3-minimum 2-phase):
// per K-step issue next tile's global loads, MFMA current buffer, write
// regs -> other buffer, ONE barrier. 512 blocks = exactly 2/CU resident.
__global__ __launch_bounds__(256, 2) void logits_mfma_kernel(
    const unsigned short* __restrict__ A,
    const unsigned short* __restrict__ B,
    const float* __restrict__ bias,
    float* __restrict__ C)
{
    __shared__ __align__(16) unsigned short As[2][128 * 64];
    __shared__ __align__(16) unsigned short Bs[2][128 * 64];

    const int tid = threadIdx.x;
    const int lane = tid & 63;
    const int wave = tid >> 6;
    const int wr = wave >> 1;
    const int wc = wave & 1;
    const int m0 = blockIdx.y * 128;
    const int n0 = blockIdx.x * 128;
    const int lr = tid >> 3;
    const int lk = tid & 7;

    floatx4 acc[4][4];
    #pragma unroll
    for (int i = 0; i < 4; ++i)
        #pragma unroll
        for (int jn = 0; jn < 4; ++jn)
            acc[i][jn] = (floatx4)(0.0f);

    uint4 ra[4], rb[4];
    auto load_tile = [&](int kt) {
        const int k0 = kt * 64;
        #pragma unroll
        for (int i = 0; i < 4; ++i) {
            const int r = lr + 32 * i;
            ra[i] = *(const uint4*)&A[(size_t)(m0 + r) * FLAT + k0 + lk * 8];
            rb[i] = *(const uint4*)&B[(size_t)(n0 + r) * FLAT + k0 + lk * 8];
        }
    };
    auto write_tile = [&](int buf) {
        #pragma unroll
        for (int i = 0; i < 4; ++i) {
            const int r = lr + 32 * i;
            *(uint4*)&As[buf][r * 64 + ((lk ^ (r & 7)) * 8)] = ra[i];
            *(uint4*)&Bs[buf][r * 64 + ((lk ^ (r & 7)) * 8)] = rb[i];
        }
    };

    load_tile(0);
    write_tile(0);
    __syncthreads();

    #pragma unroll 2
    for (int kt = 0; kt < 16; ++kt) {
        const int cur = kt & 1;
        if (kt < 15) load_tile(kt + 1);   // global loads overlap MFMA below
        #pragma unroll
        for (int s = 0; s < 2; ++s) {
            const int kg = s * 4 + (lane >> 4);
            const int sw = (kg ^ (lane & 7)) * 8;
            shortx8 af[4], bf[4];
            #pragma unroll
            for (int t = 0; t < 4; ++t) {
                af[t] = *(const shortx8*)&As[cur][(wr * 64 + t * 16 + (lane & 15)) * 64 + sw];
                bf[t] = *(const shortx8*)&Bs[cur][(wc * 64 + t * 16 + (lane & 15)) * 64 + sw];
            }
            #pragma unroll
            for (int mt = 0; mt < 4; ++mt)
                #pragma unroll
                for (int nt = 0; nt < 4; ++nt)
                    acc[mt][nt] = __builtin_amdgcn_mfma_f32_16x16x32_bf16(
                        af[mt], bf[nt], acc[mt][nt], 0, 0, 0);
        }
        if (kt < 15) {
            write_tile(cur ^ 1);          // other buffer: no read hazard
            __syncthreads();              // one barrier per K-step
        }
    }

    const int col_l = lane & 15;
    const int rg = lane >> 4;
    #pragma unroll
    for (int nt = 0; nt < 4; ++nt) {
        const int col = n0 + wc * 64 + nt * 16 + col_l;
        const float bv = bias[col];
        #pragma unroll
        for (int mt = 0; mt < 4; ++mt) {
            const int row = m0 + wr * 64 + mt * 16 + rg * 4;
            #pragma unroll
            for (int i = 0; i < 4; ++i) {
                C[(size_t)(row + i) * OUT_DIM + col] = acc[mt][nt][i] + bv;
            }
        }
    }
}

} // namespace

extern "C" void kernel_launch(void* const* d_in, const int* in_sizes, int n_in,
                              void* d_out, int out_size, void* d_ws, size_t ws_size,
                              hipStream_t stream) {
    const float* x    = (const float*)d_in[0];
    const void*  ei   = d_in[1];
    const float* h0   = (const float*)d_in[2];
    const float* Wg   = (const float*)d_in[3];
    const float* bg   = (const float*)d_in[4];
    const float* Wih  = (const float*)d_in[5];
    const float* Whh  = (const float*)d_in[6];
    const float* bih  = (const float*)d_in[7];
    const float* bhh  = (const float*)d_in[8];
    const float* Wlin = (const float*)d_in[9];
    const float* blin = (const float*)d_in[10];

    float* out = (float*)d_out;
    float* logits = out;                               // [16384, 512]
    float* next_h = out + (size_t)NUM_ENVS * OUT_DIM;  // [16384, 16, 64]

    float* wsf = (float*)d_ws;
    int* flag = (int*)(wsf + WS_FLAG);
    unsigned short* WgF = (unsigned short*)(wsf + WS_WGF);
    unsigned short* WcF = (unsigned short*)(wsf + WS_WCF);
    unsigned short* Wlb = (unsigned short*)(wsf + WS_WLB);
    unsigned short* gb  = (unsigned short*)(wsf + WS_GB);  // hb

    prep_kernel<<<2177, 256, 0, stream>>>((const int*)ei, Wg, Wih, Whh, Wlin, wsf);
    fused_gcn_gru_kernel<<<4096, 256, 0, stream>>>(x, ei, WgF, bg, h0, WcF, bih, bhh,
                                                   next_h, gb, flag);
    dim3 g2(OUT_DIM / 128, NUM_ENVS / 128);
    logits_mfma_kernel<<<g2, 256, 0, stream>>>(gb, Wlb, blin, logits);
}